// Round 4
// baseline (772.522 us; speedup 1.0000x reference)
//
#include <hip/hip_runtime.h>
#include <math.h>

// EMA along T: y[0]=x[0]; y[t] = (1-a)*y[t-1] + a*x[t], a=0.01.
// Single-pass decoupled-lookback scan:
//   - 2048 blocks, each owns one (b, k) chunk of CHUNK=32 timesteps, full C.
//   - ticket-ordered virtual block ids (atomic counter) => spin-wait on
//     lower ids is deadlock-free (lower tickets started earlier).
//   - local zero-init scan held in registers; publish aggregate; lookback
//     over predecessors (agg/inclusive with agent-scope acquire/release for
//     cross-XCD visibility); fix-up out[t] = y_loc[t] + d^(t+1)*carry.
//   - x is read exactly once, out written once: ~268 MB total HBM.

namespace {
constexpr int B = 8;
constexpr int T = 8192;
constexpr int C = 512;
constexpr float ALPHA = 0.01f;
constexpr float DECAY = 1.0f - ALPHA;   // 0.99
constexpr int CHUNK = 32;               // timesteps per block (32 float4 regs)
constexpr int K = T / CHUNK;            // 256 chunks per batch
constexpr int STRIDE4 = C / 4;          // float4 stride per timestep = 128
constexpr int TPB = C / 4;              // 128 threads, 4 channels each
constexpr int NCHUNK = B * K;           // 2048 virtual blocks

// ws layout (bytes):
constexpr size_t WS_TICKET = 0;          // 1 uint
constexpr size_t WS_STATUS = 256;        // NCHUNK uints (8 KB)
constexpr size_t WS_AGGS   = 16384;      // NCHUNK*C floats (4 MB)
constexpr size_t WS_INCS   = WS_AGGS + (size_t)NCHUNK * C * sizeof(float);
constexpr size_t WS_NEED   = WS_INCS + (size_t)NCHUNK * C * sizeof(float);
constexpr size_t WS_ZERO_BYTES = 16384;  // covers ticket + status
}

__global__ __launch_bounds__(TPB) void ema_fused_kernel(
    const float* __restrict__ x, float* __restrict__ out,
    unsigned int* __restrict__ ticket, unsigned int* __restrict__ status,
    float4* __restrict__ aggs, float4* __restrict__ incs, float decay_chunk) {
    const int tid = threadIdx.x;
    __shared__ unsigned int s_vid;
    if (tid == 0)
        s_vid = __hip_atomic_fetch_add(ticket, 1u, __ATOMIC_RELAXED,
                                       __HIP_MEMORY_SCOPE_AGENT);
    __syncthreads();
    const unsigned int vid = s_vid;
    const int b = vid & (B - 1);   // interleave the 8 chains across tickets
    const int k = vid >> 3;
    const int idx = b * K + k;

    const size_t base4 = (size_t)(b * T + k * CHUNK) * STRIDE4 + tid;
    const float4* xp = reinterpret_cast<const float4*>(x) + base4;
    float4* op = reinterpret_cast<float4*>(out) + base4;

    // ---- local zero-init scan, fully in registers ----
    float4 y[CHUNK];
#pragma unroll
    for (int t = 0; t < CHUNK; ++t) y[t] = xp[(size_t)t * STRIDE4];
    float4 run;
    if (k == 0) run = y[0];  // y_pre = x[0]: d*x0 + a*x0 = x0 seeds chunk 0
    else        run = make_float4(0.f, 0.f, 0.f, 0.f);
#pragma unroll
    for (int t = 0; t < CHUNK; ++t) {
        run.x = DECAY * run.x + ALPHA * y[t].x;
        run.y = DECAY * run.y + ALPHA * y[t].y;
        run.z = DECAY * run.z + ALPHA * y[t].z;
        run.w = DECAY * run.w + ALPHA * y[t].w;
        y[t] = run;
    }
    // run == aggregate (chunk-local end state)

    float4 carry = make_float4(0.f, 0.f, 0.f, 0.f);
    if (k == 0) {
        // publish inclusive directly
        incs[(size_t)idx * STRIDE4 + tid] = run;
        __syncthreads();  // all block stores retired to L2
        if (tid == 0) {
            __builtin_amdgcn_fence(__ATOMIC_RELEASE, "agent");
            __hip_atomic_store(&status[idx], 2u, __ATOMIC_RELAXED,
                               __HIP_MEMORY_SCOPE_AGENT);
        }
    } else {
        // publish aggregate first so successors can make progress
        aggs[(size_t)idx * STRIDE4 + tid] = run;
        __syncthreads();
        if (tid == 0) {
            __builtin_amdgcn_fence(__ATOMIC_RELEASE, "agent");
            __hip_atomic_store(&status[idx], 1u, __ATOMIC_RELAXED,
                               __HIP_MEMORY_SCOPE_AGENT);
        }
        // ---- lookback: carry = inclusive state through chunk k-1 ----
        float w = 1.f;
        int m = idx - 1;           // (b, k-1), same chain
        for (;;) {
            unsigned int s;
            do {
                s = __hip_atomic_load(&status[m], __ATOMIC_RELAXED,
                                      __HIP_MEMORY_SCOPE_AGENT);
                if (s == 0u) __builtin_amdgcn_s_sleep(1);
            } while (s == 0u);
            __builtin_amdgcn_fence(__ATOMIC_ACQUIRE, "agent");
            if (s == 2u) {
                float4 v = incs[(size_t)m * STRIDE4 + tid];
                carry.x += w * v.x; carry.y += w * v.y;
                carry.z += w * v.z; carry.w += w * v.w;
                break;
            } else {
                float4 v = aggs[(size_t)m * STRIDE4 + tid];
                carry.x += w * v.x; carry.y += w * v.y;
                carry.z += w * v.z; carry.w += w * v.w;
                w *= decay_chunk;
                --m;
            }
        }
        // inclusive_k = d^CHUNK * carry + agg_k ; publish
        float4 inc;
        inc.x = decay_chunk * carry.x + run.x;
        inc.y = decay_chunk * carry.y + run.y;
        inc.z = decay_chunk * carry.z + run.z;
        inc.w = decay_chunk * carry.w + run.w;
        incs[(size_t)idx * STRIDE4 + tid] = inc;
        __syncthreads();
        if (tid == 0) {
            __builtin_amdgcn_fence(__ATOMIC_RELEASE, "agent");
            __hip_atomic_store(&status[idx], 2u, __ATOMIC_RELAXED,
                               __HIP_MEMORY_SCOPE_AGENT);
        }
    }

    // ---- fix-up and write: out[t] = y_loc[t] + d^(t+1) * carry ----
    float w = DECAY;
#pragma unroll
    for (int t = 0; t < CHUNK; ++t) {
        float4 o = y[t];
        o.x += w * carry.x; o.y += w * carry.y;
        o.z += w * carry.z; o.w += w * carry.w;
        op[(size_t)t * STRIDE4] = o;
        w *= DECAY;
    }
}

// ---------- 3-kernel fallback (ws too small) ----------
__global__ __launch_bounds__(TPB) void ema_ends_kernel(const float* __restrict__ x,
                                                       float* __restrict__ ends) {
    const int k = blockIdx.x, b = blockIdx.y, tid = threadIdx.x;
    const float4* xp = reinterpret_cast<const float4*>(x) +
                       (size_t)(b * T + k * CHUNK) * STRIDE4 + tid;
    float4 y = (k == 0) ? xp[0] : make_float4(0.f, 0.f, 0.f, 0.f);
#pragma unroll 8
    for (int t = 0; t < CHUNK; ++t) {
        float4 v = xp[(size_t)t * STRIDE4];
        y.x = DECAY * y.x + ALPHA * v.x; y.y = DECAY * y.y + ALPHA * v.y;
        y.z = DECAY * y.z + ALPHA * v.z; y.w = DECAY * y.w + ALPHA * v.w;
    }
    reinterpret_cast<float4*>(ends)[(size_t)(b * K + k) * STRIDE4 + tid] = y;
}

__global__ __launch_bounds__(TPB) void ema_carry_kernel(float* __restrict__ ends,
                                                        float decay_chunk) {
    constexpr int CTILE = 16;
    const int b = blockIdx.x, tid = threadIdx.x;
    float4* ep = reinterpret_cast<float4*>(ends) + (size_t)b * K * STRIDE4 + tid;
    float4 y = make_float4(0.f, 0.f, 0.f, 0.f);
    for (int base = 0; base < K; base += CTILE) {
        float4 e[CTILE];
#pragma unroll
        for (int i = 0; i < CTILE; ++i) e[i] = ep[(size_t)(base + i) * STRIDE4];
#pragma unroll
        for (int i = 0; i < CTILE; ++i) {
            y.x = decay_chunk * y.x + e[i].x; y.y = decay_chunk * y.y + e[i].y;
            y.z = decay_chunk * y.z + e[i].z; y.w = decay_chunk * y.w + e[i].w;
            ep[(size_t)(base + i) * STRIDE4] = y;
        }
    }
}

__global__ __launch_bounds__(TPB) void ema_scan_kernel(const float* __restrict__ x,
                                                       const float* __restrict__ ends,
                                                       float* __restrict__ out) {
    const int k = blockIdx.x, b = blockIdx.y, tid = threadIdx.x;
    const size_t base4 = (size_t)(b * T + k * CHUNK) * STRIDE4 + tid;
    const float4* xp = reinterpret_cast<const float4*>(x) + base4;
    float4* op = reinterpret_cast<float4*>(out) + base4;
    float4 y = (k == 0) ? xp[0]
        : reinterpret_cast<const float4*>(ends)[(size_t)(b * K + (k - 1)) * STRIDE4 + tid];
#pragma unroll 8
    for (int t = 0; t < CHUNK; ++t) {
        float4 v = xp[(size_t)t * STRIDE4];
        y.x = DECAY * y.x + ALPHA * v.x; y.y = DECAY * y.y + ALPHA * v.y;
        y.z = DECAY * y.z + ALPHA * v.z; y.w = DECAY * y.w + ALPHA * v.w;
        op[(size_t)t * STRIDE4] = y;
    }
}

extern "C" void kernel_launch(void* const* d_in, const int* in_sizes, int n_in,
                              void* d_out, int out_size, void* d_ws, size_t ws_size,
                              hipStream_t stream) {
    (void)in_sizes; (void)n_in; (void)out_size;
    const float* x = reinterpret_cast<const float*>(d_in[0]);
    float* out = reinterpret_cast<float*>(d_out);
    const float decay_chunk = (float)pow((double)DECAY, (double)CHUNK);

    if (ws_size >= WS_NEED) {
        char* ws = reinterpret_cast<char*>(d_ws);
        unsigned int* ticket = reinterpret_cast<unsigned int*>(ws + WS_TICKET);
        unsigned int* status = reinterpret_cast<unsigned int*>(ws + WS_STATUS);
        float4* aggs = reinterpret_cast<float4*>(ws + WS_AGGS);
        float4* incs = reinterpret_cast<float4*>(ws + WS_INCS);
        // harness re-poisons ws to 0xAA before every launch: zero flags+ticket
        hipMemsetAsync(d_ws, 0, WS_ZERO_BYTES, stream);
        ema_fused_kernel<<<dim3(NCHUNK), dim3(TPB), 0, stream>>>(
            x, out, ticket, status, aggs, incs, decay_chunk);
    } else if (ws_size >= (size_t)B * K * C * sizeof(float)) {
        float* ends = reinterpret_cast<float*>(d_ws);
        ema_ends_kernel<<<dim3(K, B), dim3(TPB), 0, stream>>>(x, ends);
        ema_carry_kernel<<<dim3(B), dim3(TPB), 0, stream>>>(ends, decay_chunk);
        ema_scan_kernel<<<dim3(K, B), dim3(TPB), 0, stream>>>(x, ends, out);
    }
}